// Round 5
// baseline (254.966 us; speedup 1.0000x reference)
//
#include <hip/hip_runtime.h>

#define T_TOK 2048
#define HID   1024
#define FFN   2048
#define NEXP  8
#define MAX_SLOTS 40

typedef __attribute__((ext_vector_type(8))) short bf16x8;
typedef __attribute__((ext_vector_type(4))) float f32x4;

__device__ __forceinline__ short f2bf(float f) {
    unsigned u = __builtin_bit_cast(unsigned, f);
    u = (u + 0x7fffu + ((u >> 16) & 1u)) >> 16;
    return (short)u;
}

__device__ __forceinline__ float gelu_exact(float x) {
    return 0.5f * x * (1.0f + erff(x * 0.70710678118654752f));
}

// async 16B global -> LDS (DMA). LDS dest: wave-uniform base + lane*16.
__device__ __forceinline__ void async_cp16(const short* g, short* l) {
    __builtin_amdgcn_global_load_lds(
        (const __attribute__((address_space(1))) unsigned int*)g,
        (__attribute__((address_space(3))) unsigned int*)l, 16, 0, 0);
}

// ---------- prep: xcvt (bx<1024) | initout (bx<3072) | bucket (bx==3072) ----
__global__ __launch_bounds__(256) void prep_kernel(
        const float* __restrict__ x, const int* __restrict__ idx,
        const float* __restrict__ b2,
        short* __restrict__ xb, float* __restrict__ out,
        int* __restrict__ offs, int* __restrict__ cnts,
        int* __restrict__ tokl,
        int* __restrict__ slot_e, int* __restrict__ slot_t0) {
    int bx = blockIdx.x;
    int tid = threadIdx.x;
    if (bx < 1024) {                    // x f32 -> bf16
        int i = (bx * 256 + tid) * 8;
        float4 v0 = *(const float4*)(x + i);
        float4 v1 = *(const float4*)(x + i + 4);
        bf16x8 r = {f2bf(v0.x), f2bf(v0.y), f2bf(v0.z), f2bf(v0.w),
                    f2bf(v1.x), f2bf(v1.y), f2bf(v1.z), f2bf(v1.w)};
        *(bf16x8*)(xb + i) = r;
    } else if (bx < 1024 + T_TOK) {     // out[t] = b2[idx[t]]
        int t = bx - 1024;
        int e = idx[t];
        ((float4*)(out + (size_t)t * HID))[tid] =
            ((const float4*)(b2 + (size_t)e * HID))[tid];
    } else {                            // bucket + slot worklist
        __shared__ int c[NEXP], cur[NEXP], o[NEXP];
        if (tid < NEXP) { c[tid] = 0; cur[tid] = 0; }
        __syncthreads();
        for (int t = tid; t < T_TOK; t += 256) atomicAdd(&c[idx[t]], 1);
        __syncthreads();
        if (tid == 0) {
            int s = 0;
            for (int e = 0; e < NEXP; e++) { o[e] = s; s += c[e]; }
            int ns = 0;
            for (int e = 0; e < NEXP; e++)
                for (int t0 = 0; t0 < c[e]; t0 += 64) {
                    slot_e[ns] = e; slot_t0[ns] = t0; ns++;
                }
            for (; ns < MAX_SLOTS; ns++) slot_e[ns] = -1;
        }
        __syncthreads();
        if (tid < NEXP) { offs[tid] = o[tid]; cnts[tid] = c[tid]; }
        for (int t = tid; t < T_TOK; t += 256) {
            int e = idx[t];
            int p = o[e] + atomicAdd(&cur[e], 1);
            tokl[p] = t;
        }
    }
}

// ---------- fused weight transpose: W[e][K][N] f32 -> WT[e][N][K] bf16 ------
// grid (32, 32, 16): z<8 -> W1 (K=HID,N=FFN), z>=8 -> W2 (K=FFN,N=HID).
__global__ __launch_bounds__(256) void wtrans_kernel(
        const float* __restrict__ W1, const float* __restrict__ W2,
        short* __restrict__ W1T, short* __restrict__ W2T) {
    int z = blockIdx.z;
    const float* W; short* WT; int K, N, e;
    if (z < NEXP) { W = W1; WT = W1T; K = HID; N = FFN; e = z; }
    else          { W = W2; WT = W2T; K = FFN; N = HID; e = z - NEXP; }
    int n0 = blockIdx.x * 64, k0 = blockIdx.y * 64;
    if (n0 >= N || k0 >= K) return;
    const float* We = W + (size_t)e * K * N;
    short* WTe = WT + (size_t)e * N * K;
    __shared__ short Ts[64][72];
    int tid = threadIdx.x;
#pragma unroll
    for (int i = 0; i < 4; i++) {
        int c = tid + i * 256;               // [0,1024)
        int k = c >> 4, n4 = (c & 15) * 4;
        float4 v = *(const float4*)(We + (size_t)(k0 + k) * N + n0 + n4);
        short s0 = f2bf(v.x), s1 = f2bf(v.y), s2 = f2bf(v.z), s3 = f2bf(v.w);
        int ck = k >> 3, kj = k & 7;
        Ts[n4 + 0][((ck ^ (((n4 + 0) >> 3) & 7)) << 3) + kj] = s0;
        Ts[n4 + 1][((ck ^ (((n4 + 1) >> 3) & 7)) << 3) + kj] = s1;
        Ts[n4 + 2][((ck ^ (((n4 + 2) >> 3) & 7)) << 3) + kj] = s2;
        Ts[n4 + 3][((ck ^ (((n4 + 3) >> 3) & 7)) << 3) + kj] = s3;
    }
    __syncthreads();
#pragma unroll
    for (int i = 0; i < 2; i++) {
        int c = tid + i * 256;               // [0,512)
        int n = c >> 3, ck = c & 7;
        bf16x8 v = *(const bf16x8*)&Ts[n][(ck ^ ((n >> 3) & 7)) << 3];
        *(bf16x8*)(WTe + (size_t)(n0 + n) * K + k0 + ck * 8) = v;
    }
}

// ---------- GEMM1: hg = gelu(xb_gathered @ W1T^T + b1) ----------------------
// 64x64 tile, BK=32, m97-style global_load_lds staging, single buffer.
// grid (FFN/64, MAX_SLOTS), block 256.
__global__ __launch_bounds__(256) void gemm1_kernel(
        const short* __restrict__ xb, const short* __restrict__ W1T,
        const float* __restrict__ b1,
        const int* __restrict__ offs, const int* __restrict__ cnts,
        const int* __restrict__ tokl,
        const int* __restrict__ slot_e, const int* __restrict__ slot_t0,
        short* __restrict__ hg) {
    int s = blockIdx.y;
    int e = slot_e[s];
    if (e < 0) return;
    int t0 = slot_t0[s];
    int count = cnts[e];
    int off = offs[e];
    int n0 = blockIdx.x * 64;

    __shared__ short As[64 * 32];   // [row][32k], 64B rows
    __shared__ short Bs[64 * 32];
    __shared__ int stok[64];

    int tid = threadIdx.x;
    if (tid < 64) {
        int p = t0 + tid;
        stok[tid] = tokl[off + (p < count ? p : count - 1)];
    }
    __syncthreads();

    int w = tid >> 6, lane = tid & 63, l15 = lane & 15, quad = lane >> 4;
    int wm = (w >> 1) * 32, wn = (w & 1) * 32;

    // staging: wave w covers rows [w*16, w*16+16); lane: row w*16+(lane>>2), chunk lane&3
    int srow = w * 16 + (lane >> 2);
    int schunk = (lane & 3) * 8;      // shorts
    const short* gA = xb + (size_t)stok[srow] * HID + schunk;
    const short* gB = W1T + (size_t)e * FFN * HID + (size_t)(n0 + srow) * HID + schunk;
    short* lA = &As[w * 16 * 32];
    short* lB = &Bs[w * 16 * 32];

    f32x4 acc[2][2];
#pragma unroll
    for (int i = 0; i < 2; i++)
#pragma unroll
        for (int j = 0; j < 2; j++) acc[i][j] = (f32x4){0.f, 0.f, 0.f, 0.f};

    for (int kt = 0; kt < HID / 32; kt++) {
        async_cp16(gA + kt * 32, lA);
        async_cp16(gB + kt * 32, lB);
        __syncthreads();
        bf16x8 a0 = *(const bf16x8*)&As[(wm + l15) * 32 + quad * 8];
        bf16x8 a1 = *(const bf16x8*)&As[(wm + 16 + l15) * 32 + quad * 8];
        bf16x8 b0 = *(const bf16x8*)&Bs[(wn + l15) * 32 + quad * 8];
        bf16x8 b1v = *(const bf16x8*)&Bs[(wn + 16 + l15) * 32 + quad * 8];
        acc[0][0] = __builtin_amdgcn_mfma_f32_16x16x32_bf16(a0, b0, acc[0][0], 0, 0, 0);
        acc[0][1] = __builtin_amdgcn_mfma_f32_16x16x32_bf16(a0, b1v, acc[0][1], 0, 0, 0);
        acc[1][0] = __builtin_amdgcn_mfma_f32_16x16x32_bf16(a1, b0, acc[1][0], 0, 0, 0);
        acc[1][1] = __builtin_amdgcn_mfma_f32_16x16x32_bf16(a1, b1v, acc[1][1], 0, 0, 0);
        __syncthreads();
    }

#pragma unroll
    for (int mt = 0; mt < 2; mt++) {
        int rbase = wm + mt * 16 + quad * 4;
#pragma unroll
        for (int nt = 0; nt < 2; nt++) {
            int coln = n0 + wn + nt * 16 + l15;
            float bb = b1[e * FFN + coln];
#pragma unroll
            for (int r = 0; r < 4; r++) {
                int p = t0 + rbase + r;
                if (p < count) {
                    float hv = gelu_exact(acc[mt][nt][r] + bb);
                    hg[(size_t)(off + p) * FFN + coln] = f2bf(hv);
                }
            }
        }
    }
}

// ---------- GEMM2: out[tok] += hg_gathered @ W2T^T  (split-K x4) ------------
// grid (HID/64, MAX_SLOTS, 4), block 256.
__global__ __launch_bounds__(256) void gemm2_kernel(
        const short* __restrict__ hg, const short* __restrict__ W2T,
        const int* __restrict__ offs, const int* __restrict__ cnts,
        const int* __restrict__ tokl,
        const int* __restrict__ slot_e, const int* __restrict__ slot_t0,
        float* __restrict__ out) {
    int s = blockIdx.y;
    int e = slot_e[s];
    if (e < 0) return;
    int t0 = slot_t0[s];
    int ks = blockIdx.z;
    int count = cnts[e];
    int off = offs[e];
    int n0 = blockIdx.x * 64;
    int kbase = ks * (FFN / 4);

    __shared__ short As[64 * 32];
    __shared__ short Bs[64 * 32];

    int tid = threadIdx.x;
    int w = tid >> 6, lane = tid & 63, l15 = lane & 15, quad = lane >> 4;
    int wm = (w >> 1) * 32, wn = (w & 1) * 32;

    int srow = w * 16 + (lane >> 2);
    int schunk = (lane & 3) * 8;
    int grow = off + (t0 + srow < count ? t0 + srow : count - 1);
    const short* gA = hg + (size_t)grow * FFN + kbase + schunk;
    const short* gB = W2T + (size_t)e * HID * FFN + (size_t)(n0 + srow) * FFN + kbase + schunk;
    short* lA = &As[w * 16 * 32];
    short* lB = &Bs[w * 16 * 32];

    f32x4 acc[2][2];
#pragma unroll
    for (int i = 0; i < 2; i++)
#pragma unroll
        for (int j = 0; j < 2; j++) acc[i][j] = (f32x4){0.f, 0.f, 0.f, 0.f};

    for (int kt = 0; kt < FFN / 4 / 32; kt++) {
        async_cp16(gA + kt * 32, lA);
        async_cp16(gB + kt * 32, lB);
        __syncthreads();
        bf16x8 a0 = *(const bf16x8*)&As[(wm + l15) * 32 + quad * 8];
        bf16x8 a1 = *(const bf16x8*)&As[(wm + 16 + l15) * 32 + quad * 8];
        bf16x8 b0 = *(const bf16x8*)&Bs[(wn + l15) * 32 + quad * 8];
        bf16x8 b1v = *(const bf16x8*)&Bs[(wn + 16 + l15) * 32 + quad * 8];
        acc[0][0] = __builtin_amdgcn_mfma_f32_16x16x32_bf16(a0, b0, acc[0][0], 0, 0, 0);
        acc[0][1] = __builtin_amdgcn_mfma_f32_16x16x32_bf16(a0, b1v, acc[0][1], 0, 0, 0);
        acc[1][0] = __builtin_amdgcn_mfma_f32_16x16x32_bf16(a1, b0, acc[1][0], 0, 0, 0);
        acc[1][1] = __builtin_amdgcn_mfma_f32_16x16x32_bf16(a1, b1v, acc[1][1], 0, 0, 0);
        __syncthreads();
    }

#pragma unroll
    for (int mt = 0; mt < 2; mt++) {
        int rbase = wm + mt * 16 + quad * 4;
#pragma unroll
        for (int nt = 0; nt < 2; nt++) {
            int coln = n0 + wn + nt * 16 + l15;
#pragma unroll
            for (int r = 0; r < 4; r++) {
                int p = t0 + rbase + r;
                if (p < count) {
                    int tok = tokl[off + p];
                    atomicAdd(out + (size_t)tok * HID + coln, acc[mt][nt][r]);
                }
            }
        }
    }
}

extern "C" void kernel_launch(void* const* d_in, const int* in_sizes, int n_in,
                              void* d_out, int out_size, void* d_ws, size_t ws_size,
                              hipStream_t stream) {
    const float* x   = (const float*)d_in[0];
    const int*   idx = (const int*)d_in[1];
    const float* W1  = (const float*)d_in[2];
    const float* b1  = (const float*)d_in[3];
    const float* W2  = (const float*)d_in[4];
    const float* b2  = (const float*)d_in[5];
    float* out = (float*)d_out;

    const size_t META = 32768;
    int*   offs    = (int*)d_ws;
    int*   cnts    = offs + 8;
    int*   tokl    = offs + 16;         // [2048]
    int*   slot_e  = offs + 16 + T_TOK; // [MAX_SLOTS]
    int*   slot_t0 = slot_e + MAX_SLOTS;
    char*  base    = (char*)d_ws + META;
    short* xb  = (short*)base;                                   // 4 MB
    short* hg  = (short*)(base + (size_t)T_TOK * HID * 2);       // 8 MB
    short* W1T = (short*)(base + (size_t)T_TOK * HID * 2 + (size_t)T_TOK * FFN * 2);
    short* W2T = W1T + (size_t)NEXP * FFN * HID;                 // 32 MB each

    prep_kernel<<<1024 + T_TOK + 1, 256, 0, stream>>>(
        x, idx, b2, xb, out, offs, cnts, tokl, slot_e, slot_t0);
    wtrans_kernel<<<dim3(32, 32, 16), 256, 0, stream>>>(W1, W2, W1T, W2T);

    gemm1_kernel<<<dim3(FFN / 64, MAX_SLOTS), 256, 0, stream>>>(
        xb, W1T, b1, offs, cnts, tokl, slot_e, slot_t0, hg);
    gemm2_kernel<<<dim3(HID / 64, MAX_SLOTS, 4), 256, 0, stream>>>(
        hg, W2T, offs, cnts, tokl, slot_e, slot_t0, out);
}

// Round 6
// 224.601 us; speedup vs baseline: 1.1352x; 1.1352x over previous
//
#include <hip/hip_runtime.h>

#define T_TOK 2048
#define HID   1024
#define FFN   2048
#define NEXP  8
#define MAX_SLOTS 40

typedef __attribute__((ext_vector_type(8))) short bf16x8;
typedef __attribute__((ext_vector_type(4))) float f32x4;

__device__ __forceinline__ short f2bf(float f) {
    unsigned u = __builtin_bit_cast(unsigned, f);
    u = (u + 0x7fffu + ((u >> 16) & 1u)) >> 16;
    return (short)u;
}

__device__ __forceinline__ float gelu_exact(float x) {
    return 0.5f * x * (1.0f + erff(x * 0.70710678118654752f));
}

// async 16B global -> LDS DMA. LDS dest: wave-uniform base + lane*16.
__device__ __forceinline__ void async_cp16(const short* g, short* l) {
    __builtin_amdgcn_global_load_lds(
        (const __attribute__((address_space(1))) unsigned int*)g,
        (__attribute__((address_space(3))) unsigned int*)l, 16, 0, 0);
}

// ---- weight transpose body: W[e][K][N] f32 -> tiled bf16 panels -----------
// WT layout: [e][npanel=N/128][kpanel=K/64][kc=8][n=128][k8=8]  (8KB/k-panel)
// Register-only transpose: coalesced 1KB row reads, contiguous tile writes.
__device__ __forceinline__ void wtrans_body(
        const float* __restrict__ W, short* __restrict__ WT,
        int K, int N, int e, int kblk, int nblk) {
    int tid = threadIdx.x;
    int w = tid >> 6, l = tid & 63;
    int kb = kblk * 32 + w * 8;               // this wave: 8 k-rows
    int n4 = nblk * 256 + l * 4;              // this lane: 4 n-cols
    const float* src = W + (size_t)e * K * N + (size_t)kb * N + n4;
    float4 v[8];
#pragma unroll
    for (int r = 0; r < 8; r++)
        v[r] = *(const float4*)(src + (size_t)r * N);
    int kpanel = kb >> 6;
    int kc = (kb >> 3) & 7;
    int npanel = n4 >> 7;
    int n_in = n4 & 127;
    int kpanels = K >> 6;
    short* dst = WT + (size_t)e * K * N
               + ((size_t)npanel * kpanels + kpanel) * 8192
               + kc * 1024 + n_in * 8;
#pragma unroll
    for (int j = 0; j < 4; j++) {
        bf16x8 o = {f2bf(((const float*)&v[0])[j]), f2bf(((const float*)&v[1])[j]),
                    f2bf(((const float*)&v[2])[j]), f2bf(((const float*)&v[3])[j]),
                    f2bf(((const float*)&v[4])[j]), f2bf(((const float*)&v[5])[j]),
                    f2bf(((const float*)&v[6])[j]), f2bf(((const float*)&v[7])[j])};
        *(bf16x8*)(dst + j * 8) = o;
    }
}

// ---- fused prep: wtrans W1 | wtrans W2 | xcvt | initout | bucket ----------
__global__ __launch_bounds__(256) void prep_kernel(
        const float* __restrict__ x, const int* __restrict__ idx,
        const float* __restrict__ b2,
        const float* __restrict__ W1, const float* __restrict__ W2,
        short* __restrict__ xb, float* __restrict__ out,
        short* __restrict__ W1T, short* __restrict__ W2T,
        int* __restrict__ offs, int* __restrict__ cnts,
        int* __restrict__ tokl,
        int* __restrict__ slot_e, int* __restrict__ slot_t0) {
    int bx = blockIdx.x;
    int tid = threadIdx.x;
    if (bx < 2048) {                       // W1: 8e x (32 kblk x 8 nblk)
        int e = bx >> 8, rem = bx & 255;
        wtrans_body(W1, W1T, HID, FFN, e, rem & 31, rem >> 5);
    } else if (bx < 4096) {                // W2: 8e x (64 kblk x 4 nblk)
        int b = bx - 2048;
        int e = b >> 8, rem = b & 255;
        wtrans_body(W2, W2T, FFN, HID, e, rem & 63, rem >> 6);
    } else if (bx < 5120) {                // x f32 -> bf16
        int i = ((bx - 4096) * 256 + tid) * 8;
        float4 v0 = *(const float4*)(x + i);
        float4 v1 = *(const float4*)(x + i + 4);
        bf16x8 r = {f2bf(v0.x), f2bf(v0.y), f2bf(v0.z), f2bf(v0.w),
                    f2bf(v1.x), f2bf(v1.y), f2bf(v1.z), f2bf(v1.w)};
        *(bf16x8*)(xb + i) = r;
    } else if (bx < 7168) {                // out[t] = b2[idx[t]]
        int t = bx - 5120;
        int e = idx[t];
        ((float4*)(out + (size_t)t * HID))[tid] =
            ((const float4*)(b2 + (size_t)e * HID))[tid];
    } else {                               // bucket + slot worklist
        __shared__ int c[NEXP], cur[NEXP], o[NEXP];
        if (tid < NEXP) { c[tid] = 0; cur[tid] = 0; }
        __syncthreads();
        for (int t = tid; t < T_TOK; t += 256) atomicAdd(&c[idx[t]], 1);
        __syncthreads();
        if (tid == 0) {
            int s = 0;
            for (int e = 0; e < NEXP; e++) { o[e] = s; s += c[e]; }
            int ns = 0;
            for (int e = 0; e < NEXP; e++)
                for (int t0 = 0; t0 < c[e]; t0 += 64) {
                    slot_e[ns] = e; slot_t0[ns] = t0; ns++;
                }
            for (; ns < MAX_SLOTS; ns++) slot_e[ns] = -1;
        }
        __syncthreads();
        if (tid < NEXP) { offs[tid] = o[tid]; cnts[tid] = c[tid]; }
        for (int t = tid; t < T_TOK; t += 256) {
            int e = idx[t];
            int p = o[e] + atomicAdd(&cur[e], 1);
            tokl[p] = t;
        }
    }
}

// ---- GEMM1: hg = gelu(xb_gathered @ W1T + b1) ------------------------------
// block 64m x 128n, BK=64, DMA staging, waves 2x2 (32m x 64n each).
// grid (FFN/128, MAX_SLOTS).
__global__ __launch_bounds__(256) void gemm1_kernel(
        const short* __restrict__ xb, const short* __restrict__ W1T,
        const float* __restrict__ b1,
        const int* __restrict__ offs, const int* __restrict__ cnts,
        const int* __restrict__ tokl,
        const int* __restrict__ slot_e, const int* __restrict__ slot_t0,
        short* __restrict__ hg) {
    int s = blockIdx.y;
    int e = slot_e[s];
    if (e < 0) return;
    int t0 = slot_t0[s], count = cnts[e], off = offs[e];
    int n0 = blockIdx.x * 128;

    __shared__ short As[64 * 64];        // [64m][64k], 128B rows, chunk-rotated
    __shared__ short Bs[8 * 128 * 8];    // [8kc][128n][8k] linear panel image
    __shared__ int stok[64];

    int tid = threadIdx.x;
    if (tid < 64) {
        int p = t0 + tid;
        stok[tid] = tokl[off + (p < count ? p : count - 1)];
    }
    __syncthreads();

    int w = tid >> 6, l = tid & 63, l15 = l & 15, quad = l >> 4;
    int wm = (w >> 1) * 32, wn = (w & 1) * 64;

    // A staging: 2 instrs/wave; instr i: row m = w*16+i*8+(l>>3), slot chunk l&7
    int m0 = w * 16 + (l >> 3), m1 = m0 + 8;
    int cs = l & 7;
    int c0 = (cs - m0) & 7, c1 = (cs - m1) & 7;   // chunk rotation by row
    const short* gA0 = xb + (size_t)stok[m0] * HID + c0 * 8;
    const short* gA1 = xb + (size_t)stok[m1] * HID + c1 * 8;
    short* lA0 = As + w * 1024 + l * 8;
    short* lA1 = lA0 + 512;

    // B staging: 4 instrs/wave covering kc {2w,2w+1} x n-halves
    const short* Bpan = W1T + (size_t)e * (FFN * HID)
                      + (size_t)(n0 >> 7) * ((HID >> 6) * 8192);
    int bo0 = (2 * w) * 1024 + l * 8;
    int bo1 = bo0 + 1024;
    int bo2 = bo0 + 512;
    int bo3 = bo1 + 512;

    f32x4 acc[2][4];
#pragma unroll
    for (int i = 0; i < 2; i++)
#pragma unroll
        for (int j = 0; j < 4; j++) acc[i][j] = (f32x4){0.f, 0.f, 0.f, 0.f};

    for (int kt = 0; kt < HID / 64; kt++) {
        const short* bp = Bpan + kt * 8192;
        async_cp16(gA0, lA0);
        async_cp16(gA1, lA1);
        async_cp16(bp + bo0, Bs + bo0);
        async_cp16(bp + bo1, Bs + bo1);
        async_cp16(bp + bo2, Bs + bo2);
        async_cp16(bp + bo3, Bs + bo3);
        gA0 += 64; gA1 += 64;
        __syncthreads();
        bf16x8 a[2][2], b[2][4];
#pragma unroll
        for (int kk = 0; kk < 2; kk++) {
#pragma unroll
            for (int mt = 0; mt < 2; mt++) {
                int m = wm + mt * 16 + l15;
                a[kk][mt] = *(const bf16x8*)&As[m * 64 + (((kk * 4 + quad) + m) & 7) * 8];
            }
#pragma unroll
            for (int nt = 0; nt < 4; nt++) {
                int n = wn + nt * 16 + l15;
                b[kk][nt] = *(const bf16x8*)&Bs[(kk * 4 + quad) * 1024 + n * 8];
            }
        }
#pragma unroll
        for (int kk = 0; kk < 2; kk++)
#pragma unroll
            for (int mt = 0; mt < 2; mt++)
#pragma unroll
                for (int nt = 0; nt < 4; nt++)
                    acc[mt][nt] = __builtin_amdgcn_mfma_f32_16x16x32_bf16(
                        a[kk][mt], b[kk][nt], acc[mt][nt], 0, 0, 0);
        __syncthreads();
    }

    const float* b1e = b1 + e * FFN + n0;
#pragma unroll
    for (int mt = 0; mt < 2; mt++) {
        int rbase = wm + mt * 16 + quad * 4;
#pragma unroll
        for (int nt = 0; nt < 4; nt++) {
            int coln = wn + nt * 16 + l15;
            float bb = b1e[coln];
#pragma unroll
            for (int r = 0; r < 4; r++) {
                int p = t0 + rbase + r;
                if (p < count)
                    hg[(size_t)(off + p) * FFN + n0 + coln] =
                        f2bf(gelu_exact(acc[mt][nt][r] + bb));
            }
        }
    }
}

// ---- GEMM2: out[tok] += hg_gathered @ W2T  (split-K x2, atomic) ------------
// grid (HID/128, MAX_SLOTS, 2).
__global__ __launch_bounds__(256) void gemm2_kernel(
        const short* __restrict__ hg, const short* __restrict__ W2T,
        const int* __restrict__ offs, const int* __restrict__ cnts,
        const int* __restrict__ tokl,
        const int* __restrict__ slot_e, const int* __restrict__ slot_t0,
        float* __restrict__ out) {
    int s = blockIdx.y;
    int e = slot_e[s];
    if (e < 0) return;
    int t0 = slot_t0[s], count = cnts[e], off = offs[e];
    int ks = blockIdx.z;
    int n0 = blockIdx.x * 128;

    __shared__ short As[64 * 64];
    __shared__ short Bs[8 * 128 * 8];

    int tid = threadIdx.x;
    int w = tid >> 6, l = tid & 63, l15 = l & 15, quad = l >> 4;
    int wm = (w >> 1) * 32, wn = (w & 1) * 64;

    int m0 = w * 16 + (l >> 3), m1 = m0 + 8;
    int cs = l & 7;
    int c0 = (cs - m0) & 7, c1 = (cs - m1) & 7;
    int g0 = off + (t0 + m0 < count ? t0 + m0 : count - 1);
    int g1 = off + (t0 + m1 < count ? t0 + m1 : count - 1);
    const short* gA0 = hg + (size_t)g0 * FFN + ks * 1024 + c0 * 8;
    const short* gA1 = hg + (size_t)g1 * FFN + ks * 1024 + c1 * 8;
    short* lA0 = As + w * 1024 + l * 8;
    short* lA1 = lA0 + 512;

    const short* Bpan = W2T + (size_t)e * (FFN * HID)
                      + (size_t)(n0 >> 7) * ((FFN >> 6) * 8192)
                      + (size_t)ks * 16 * 8192;
    int bo0 = (2 * w) * 1024 + l * 8;
    int bo1 = bo0 + 1024;
    int bo2 = bo0 + 512;
    int bo3 = bo1 + 512;

    f32x4 acc[2][4];
#pragma unroll
    for (int i = 0; i < 2; i++)
#pragma unroll
        for (int j = 0; j < 4; j++) acc[i][j] = (f32x4){0.f, 0.f, 0.f, 0.f};

    for (int kt = 0; kt < 16; kt++) {
        const short* bp = Bpan + kt * 8192;
        async_cp16(gA0, lA0);
        async_cp16(gA1, lA1);
        async_cp16(bp + bo0, Bs + bo0);
        async_cp16(bp + bo1, Bs + bo1);
        async_cp16(bp + bo2, Bs + bo2);
        async_cp16(bp + bo3, Bs + bo3);
        gA0 += 64; gA1 += 64;
        __syncthreads();
        bf16x8 a[2][2], b[2][4];
#pragma unroll
        for (int kk = 0; kk < 2; kk++) {
#pragma unroll
            for (int mt = 0; mt < 2; mt++) {
                int m = wm + mt * 16 + l15;
                a[kk][mt] = *(const bf16x8*)&As[m * 64 + (((kk * 4 + quad) + m) & 7) * 8];
            }
#pragma unroll
            for (int nt = 0; nt < 4; nt++) {
                int n = wn + nt * 16 + l15;
                b[kk][nt] = *(const bf16x8*)&Bs[(kk * 4 + quad) * 1024 + n * 8];
            }
        }
#pragma unroll
        for (int kk = 0; kk < 2; kk++)
#pragma unroll
            for (int mt = 0; mt < 2; mt++)
#pragma unroll
                for (int nt = 0; nt < 4; nt++)
                    acc[mt][nt] = __builtin_amdgcn_mfma_f32_16x16x32_bf16(
                        a[kk][mt], b[kk][nt], acc[mt][nt], 0, 0, 0);
        __syncthreads();
    }

#pragma unroll
    for (int mt = 0; mt < 2; mt++) {
        int rbase = wm + mt * 16 + quad * 4;
#pragma unroll
        for (int nt = 0; nt < 4; nt++) {
            int coln = n0 + wn + nt * 16 + l15;
#pragma unroll
            for (int r = 0; r < 4; r++) {
                int p = t0 + rbase + r;
                if (p < count) {
                    int tok = tokl[off + p];
                    atomicAdd(out + (size_t)tok * HID + coln, acc[mt][nt][r]);
                }
            }
        }
    }
}

extern "C" void kernel_launch(void* const* d_in, const int* in_sizes, int n_in,
                              void* d_out, int out_size, void* d_ws, size_t ws_size,
                              hipStream_t stream) {
    const float* x   = (const float*)d_in[0];
    const int*   idx = (const int*)d_in[1];
    const float* W1  = (const float*)d_in[2];
    const float* b1  = (const float*)d_in[3];
    const float* W2  = (const float*)d_in[4];
    const float* b2  = (const float*)d_in[5];
    float* out = (float*)d_out;

    const size_t META = 32768;
    int*   offs    = (int*)d_ws;
    int*   cnts    = offs + 8;
    int*   tokl    = offs + 16;          // [2048]
    int*   slot_e  = offs + 16 + T_TOK;  // [MAX_SLOTS]
    int*   slot_t0 = slot_e + MAX_SLOTS;
    char*  base    = (char*)d_ws + META;
    short* xb  = (short*)base;                                    // 4 MB
    short* hg  = (short*)(base + (size_t)T_TOK * HID * 2);        // 8 MB
    short* W1T = (short*)(base + (size_t)T_TOK * HID * 2 + (size_t)T_TOK * FFN * 2);
    short* W2T = W1T + (size_t)NEXP * FFN * HID;                  // 32 MB each

    // blocks: [0,2048) W1-trans | [2048,4096) W2-trans | [4096,5120) xcvt
    //         [5120,7168) initout | 7168 bucket
    prep_kernel<<<7169, 256, 0, stream>>>(
        x, idx, b2, W1, W2, xb, out, W1T, W2T,
        offs, cnts, tokl, slot_e, slot_t0);

    gemm1_kernel<<<dim3(FFN / 128, MAX_SLOTS), 256, 0, stream>>>(
        xb, W1T, b1, offs, cnts, tokl, slot_e, slot_t0, hg);
    gemm2_kernel<<<dim3(HID / 128, MAX_SLOTS, 2), 256, 0, stream>>>(
        hg, W2T, offs, cnts, tokl, slot_e, slot_t0, out);
}